// Round 1
// 717.038 us; speedup vs baseline: 1.0229x; 1.0229x over previous
//
#include <hip/hip_runtime.h>

#define TT   512
#define DIN  2048
#define NH1  128
#define NH2  64
#define NB   64

typedef __attribute__((ext_vector_type(8))) __bf16 bf16x8;
typedef __attribute__((ext_vector_type(4))) float f32x4;
typedef __attribute__((ext_vector_type(2))) float f32x2;

__device__ __forceinline__ float tanh_fast(float x) {
    x = fminf(fmaxf(x, -15.0f), 15.0f);
    float e = __expf(2.0f * x);
    return (e - 1.0f) / (e + 1.0f);
}

__device__ __forceinline__ float rlane(float v, int l) {
    return __int_as_float(__builtin_amdgcn_readlane(__float_as_int(v), l));
}

// Packed fp32 FMA: 2 IEEE FMAs per VALU instruction (CDNA packed-f32 path).
// clang does not reliably form v_pk_fma_f32 from scalar fmaf, so force it.
__device__ __forceinline__ void pkfma(f32x2& acc, f32x2 w, f32x2 h) {
    asm("v_pk_fma_f32 %0, %1, %2, %0" : "+v"(acc) : "v"(w), "v"(h));
}

// Barrier WITHOUT vmcnt drain: LDS ordering only. Global loads stay in flight.
#define BAR() asm volatile("s_waitcnt lgkmcnt(0)\n\ts_barrier" ::: "memory")

// ---------------------------------------------------------------------------
// Kernel A: xp1 = x @ W_ih1^T + b  via 3-term bf16-split MFMA (~fp32 precision)
//   (unchanged from previous round — known-passing)
// ---------------------------------------------------------------------------
__global__ __launch_bounds__(256, 1) void xp1_gemm(const float* __restrict__ x,
                                                   const float* __restrict__ W,
                                                   const float* __restrict__ bih1,
                                                   const float* __restrict__ bhh1,
                                                   float* __restrict__ xp1) {
    __shared__ __align__(16) __bf16 wl[2][NH1][40];   // [plane][n][k pad 40]

    const int tid  = threadIdx.x;
    const int lane = tid & 63;
    const int wv   = tid >> 6;
    const int quad = lane >> 4;
    const int l16  = lane & 15;
    const int m0   = blockIdx.x * 128 + wv * 32;

    const int wr = tid >> 1;         // W stage: row
    const int wk = (tid & 1) * 16;   // W stage: k offset (16 fp32 per thread)

    float bias[8];
#pragma unroll
    for (int nt = 0; nt < 8; ++nt)
        bias[nt] = bih1[nt * 16 + l16] + bhh1[nt * 16 + l16];

    f32x4 acc[2][8];
#pragma unroll
    for (int ms = 0; ms < 2; ++ms)
#pragma unroll
        for (int nt = 0; nt < 8; ++nt)
            acc[ms][nt] = (f32x4){0.f, 0.f, 0.f, 0.f};

    const float* xr0 = x + (size_t)(m0 + l16) * DIN + quad * 8;
    const float* xr1 = x + (size_t)(m0 + 16 + l16) * DIN + quad * 8;
    const float* wp  = W + (size_t)wr * DIN + wk;

    // preload chunk 0
    float4 xa0 = *(const float4*)(xr0);
    float4 xb0 = *(const float4*)(xr0 + 4);
    float4 xa1 = *(const float4*)(xr1);
    float4 xb1 = *(const float4*)(xr1 + 4);
    float4 w0  = *(const float4*)(wp);
    float4 w1  = *(const float4*)(wp + 4);
    float4 w2  = *(const float4*)(wp + 8);
    float4 w3  = *(const float4*)(wp + 12);

    for (int kc = 0; kc < DIN; kc += 32) {
        // ---- convert & store W hi/lo planes (vmcnt wait auto-inserted)
        {
            float wf[16] = {w0.x, w0.y, w0.z, w0.w, w1.x, w1.y, w1.z, w1.w,
                            w2.x, w2.y, w2.z, w2.w, w3.x, w3.y, w3.z, w3.w};
            bf16x8 hv0, lv0, hv1, lv1;
#pragma unroll
            for (int j = 0; j < 8; ++j) {
                __bf16 h = (__bf16)wf[j];
                hv0[j] = h;
                lv0[j] = (__bf16)(wf[j] - (float)h);
            }
#pragma unroll
            for (int j = 0; j < 8; ++j) {
                __bf16 h = (__bf16)wf[8 + j];
                hv1[j] = h;
                lv1[j] = (__bf16)(wf[8 + j] - (float)h);
            }
            *(bf16x8*)&wl[0][wr][wk]     = hv0;
            *(bf16x8*)&wl[0][wr][wk + 8] = hv1;
            *(bf16x8*)&wl[1][wr][wk]     = lv0;
            *(bf16x8*)&wl[1][wr][wk + 8] = lv1;
        }
        BAR();

        // ---- convert current x to A-frags (before regs are overwritten)
        bf16x8 ah0, al0, ah1, al1;
        {
            float f0[8] = {xa0.x, xa0.y, xa0.z, xa0.w, xb0.x, xb0.y, xb0.z, xb0.w};
            float f1[8] = {xa1.x, xa1.y, xa1.z, xa1.w, xb1.x, xb1.y, xb1.z, xb1.w};
#pragma unroll
            for (int j = 0; j < 8; ++j) {
                __bf16 h0 = (__bf16)f0[j];
                ah0[j] = h0;
                al0[j] = (__bf16)(f0[j] - (float)h0);
                __bf16 h1 = (__bf16)f1[j];
                ah1[j] = h1;
                al1[j] = (__bf16)(f1[j] - (float)h1);
            }
        }

        // ---- prefetch next chunk (stays in flight through the MFMAs)
        if (kc + 32 < DIN) {
            xa0 = *(const float4*)(xr0 + kc + 32);
            xb0 = *(const float4*)(xr0 + kc + 36);
            xa1 = *(const float4*)(xr1 + kc + 32);
            xb1 = *(const float4*)(xr1 + kc + 36);
            w0  = *(const float4*)(wp + kc + 32);
            w1  = *(const float4*)(wp + kc + 36);
            w2  = *(const float4*)(wp + kc + 40);
            w3  = *(const float4*)(wp + kc + 44);
        }

        // ---- B-frags from LDS + 3-term MFMAs
#pragma unroll
        for (int nt = 0; nt < 8; ++nt) {
            bf16x8 bh = *(bf16x8*)&wl[0][nt * 16 + l16][quad * 8];
            bf16x8 bl = *(bf16x8*)&wl[1][nt * 16 + l16][quad * 8];
            acc[0][nt] = __builtin_amdgcn_mfma_f32_16x16x32_bf16(ah0, bh, acc[0][nt], 0, 0, 0);
            acc[0][nt] = __builtin_amdgcn_mfma_f32_16x16x32_bf16(al0, bh, acc[0][nt], 0, 0, 0);
            acc[0][nt] = __builtin_amdgcn_mfma_f32_16x16x32_bf16(ah0, bl, acc[0][nt], 0, 0, 0);
            acc[1][nt] = __builtin_amdgcn_mfma_f32_16x16x32_bf16(ah1, bh, acc[1][nt], 0, 0, 0);
            acc[1][nt] = __builtin_amdgcn_mfma_f32_16x16x32_bf16(al1, bh, acc[1][nt], 0, 0, 0);
            acc[1][nt] = __builtin_amdgcn_mfma_f32_16x16x32_bf16(ah1, bl, acc[1][nt], 0, 0, 0);
        }
        BAR();   // all reads done before next chunk's LDS overwrite
    }

    // ---- epilogue: C/D layout col=lane&15, row=quad*4+reg [m89-verified]
#pragma unroll
    for (int ms = 0; ms < 2; ++ms) {
        const int mb = m0 + ms * 16 + quad * 4;
#pragma unroll
        for (int nt = 0; nt < 8; ++nt) {
#pragma unroll
            for (int r = 0; r < 4; ++r)
                xp1[(size_t)(mb + r) * NH1 + nt * 16 + l16] = acc[ms][nt][r] + bias[nt];
        }
    }
}

// ---------------------------------------------------------------------------
// Kernel B: fused 2-layer scan + FC head. One block per batch elem, 4 waves.
// v2: broadcast via wave-UNIFORM ds_read_b128 (LDS HW broadcast, conflict-free,
// runs on the LDS pipe) + v_pk_fma_f32 (2 MACs/instr). This removes ALL
// per-step v_readlane traffic (previously 2 VALU instrs per MAC: readlane+fma,
// ~256 VALU/step/wave + SGPR-write hazards). h2 state also routed through LDS
// (h2buf) so wave3 uses the same pattern. Accumulator partition (k mod 4) and
// final (a0+a1)+(a2+a3) order preserved -> numerics equivalent to v1.
// BAR() = lgkm-only barrier; xp1 prefetch batched 8 steps (unchanged).
// ---------------------------------------------------------------------------
__global__ __launch_bounds__(256, 1) void rnn_scan(
        const float* __restrict__ xp1,  const float* __restrict__ Whh1,
        const float* __restrict__ Wih2, const float* __restrict__ Whh2,
        const float* __restrict__ bih2, const float* __restrict__ bhh2,
        const float* __restrict__ Wfc1, const float* __restrict__ bfc1,
        const float* __restrict__ Wfc2, const float* __restrict__ bfc2,
        float* __restrict__ out) {
    __shared__ __align__(16) float h1buf[2][NH1];
    __shared__ __align__(16) float xp2buf[2][NH2];
    __shared__ __align__(16) float h2buf[2][NH2];

    const int tid  = threadIdx.x;
    const int lane = tid & 63;
    const int wv   = tid >> 6;
    const int b    = blockIdx.x;

    // Per-lane weight row as aligned pairs (VGPR pairs for v_pk_fma_f32).
    f32x2 w2[64];
    float b2 = 0.0f;

    if (wv <= 1) {
        const int row = wv * 64 + lane;
        const float4* src = (const float4*)(Whh1 + (size_t)row * NH1);
#pragma unroll
        for (int i = 0; i < 32; ++i) {
            float4 v = src[i];
            w2[2 * i]     = (f32x2){v.x, v.y};
            w2[2 * i + 1] = (f32x2){v.z, v.w};
        }
    } else if (wv == 2) {
        const float4* src = (const float4*)(Wih2 + (size_t)lane * NH1);
#pragma unroll
        for (int i = 0; i < 32; ++i) {
            float4 v = src[i];
            w2[2 * i]     = (f32x2){v.x, v.y};
            w2[2 * i + 1] = (f32x2){v.z, v.w};
        }
        b2 = bih2[lane] + bhh2[lane];
    } else {
        const float4* src = (const float4*)(Whh2 + (size_t)lane * NH2);
#pragma unroll
        for (int i = 0; i < 16; ++i) {
            float4 v = src[i];
            w2[2 * i]     = (f32x2){v.x, v.y};
            w2[2 * i + 1] = (f32x2){v.z, v.w};
        }
    }

    if (tid < 128) h1buf[0][tid] = 0.0f;
    if (tid < 64)  { h2buf[0][tid] = 0.0f; h2buf[1][tid] = 0.0f; }

    const int row = wv * 64 + lane;
    const float* xprow = xp1 + ((size_t)b * TT) * NH1 + row;

    float xr[8], xrn[8];
    if (wv <= 1) {
#pragma unroll
        for (int j = 0; j < 8; ++j) xr[j] = xprow[(size_t)j * NH1];
    }

    __syncthreads();   // one-time init barrier

    for (int g = 0; g < 64; ++g) {
        if (wv <= 1 && g < 63) {
            const size_t t0 = (size_t)(g + 1) * 8;
#pragma unroll
            for (int j = 0; j < 8; ++j) xrn[j] = xprow[(t0 + j) * NH1];
        }
#pragma unroll
        for (int j = 0; j < 8; ++j) {           // step s = 8g + j + 1
            const int s   = 8 * g + j + 1;
            const int cur = j & 1;
            const int nxt = cur ^ 1;
            if (wv <= 1) {
                // h1[s] = tanh(xp1[s] + Whh1 . h1[s-1]); h1[s-1] in h1buf[cur]
                f32x2 aA = (f32x2){xr[j], 0.0f};
                f32x2 aB = (f32x2){0.0f, 0.0f};
#pragma unroll
                for (int i = 0; i < 32; ++i) {
                    float4 h4 = *(const float4*)&h1buf[cur][4 * i];  // uniform: HW broadcast
                    pkfma(aA, w2[2 * i],     (f32x2){h4.x, h4.y});
                    pkfma(aB, w2[2 * i + 1], (f32x2){h4.z, h4.w});
                }
                float hv = tanh_fast((aA.x + aA.y) + (aB.x + aB.y));
                h1buf[nxt][row] = hv;
            } else if (wv == 2) {
                if (s >= 2) {
                    // xp2[s-1] = b2 + Wih2 . h1[s-1]
                    f32x2 aA = (f32x2){b2, 0.0f};
                    f32x2 aB = (f32x2){0.0f, 0.0f};
#pragma unroll
                    for (int i = 0; i < 32; ++i) {
                        float4 h4 = *(const float4*)&h1buf[cur][4 * i];
                        pkfma(aA, w2[2 * i],     (f32x2){h4.x, h4.y});
                        pkfma(aB, w2[2 * i + 1], (f32x2){h4.z, h4.w});
                    }
                    xp2buf[j & 1][lane] = (aA.x + aA.y) + (aB.x + aB.y);
                }
            } else {
                if (s >= 3) {
                    // h2[s-2] = tanh(xp2[s-2] + Whh2 . h2[s-3]); state in h2buf[cur]
                    float xv = xp2buf[(j + 1) & 1][lane];
                    f32x2 aA = (f32x2){0.0f, 0.0f};
                    f32x2 aB = (f32x2){0.0f, 0.0f};
#pragma unroll
                    for (int i = 0; i < 16; ++i) {
                        float4 h4 = *(const float4*)&h2buf[cur][4 * i];
                        pkfma(aA, w2[2 * i],     (f32x2){h4.x, h4.y});
                        pkfma(aB, w2[2 * i + 1], (f32x2){h4.z, h4.w});
                    }
                    float h2v = tanh_fast(xv + ((aA.x + aA.y) + (aB.x + aB.y)));
                    h2buf[nxt][lane] = h2v;
                }
            }
            BAR();
        }
        if (wv <= 1 && g < 63) {
#pragma unroll
            for (int j = 0; j < 8; ++j) xr[j] = xrn[j];
        }
    }

    // tail s = 513: wave2 makes xp2[512]; wave3 makes h2[511]
    {
        if (wv == 2) {
            f32x2 aA = (f32x2){b2, 0.0f};
            f32x2 aB = (f32x2){0.0f, 0.0f};
#pragma unroll
            for (int i = 0; i < 32; ++i) {
                float4 h4 = *(const float4*)&h1buf[0][4 * i];   // H1[512]
                pkfma(aA, w2[2 * i],     (f32x2){h4.x, h4.y});
                pkfma(aB, w2[2 * i + 1], (f32x2){h4.z, h4.w});
            }
            xp2buf[0][lane] = (aA.x + aA.y) + (aB.x + aB.y);    // xp2[512]+bias
        } else if (wv == 3) {
            float xv = xp2buf[1][lane];                         // xp2[511]+bias
            f32x2 aA = (f32x2){0.0f, 0.0f};
            f32x2 aB = (f32x2){0.0f, 0.0f};
#pragma unroll
            for (int i = 0; i < 16; ++i) {
                float4 h4 = *(const float4*)&h2buf[0][4 * i];   // h2[510]
                pkfma(aA, w2[2 * i],     (f32x2){h4.x, h4.y});
                pkfma(aB, w2[2 * i + 1], (f32x2){h4.z, h4.w});
            }
            float h2v = tanh_fast(xv + ((aA.x + aA.y) + (aB.x + aB.y)));  // h2[511]
            h2buf[1][lane] = h2v;
        }
        BAR();
    }
    // tail s = 514: wave3 makes H2[512]; then FC head
    if (wv == 3) {
        float xv = xp2buf[0][lane];                             // xp2[512]+bias
        f32x2 aA = (f32x2){0.0f, 0.0f};
        f32x2 aB = (f32x2){0.0f, 0.0f};
#pragma unroll
        for (int i = 0; i < 16; ++i) {
            float4 h4 = *(const float4*)&h2buf[1][4 * i];       // h2[511]
            pkfma(aA, w2[2 * i],     (f32x2){h4.x, h4.y});
            pkfma(aB, w2[2 * i + 1], (f32x2){h4.z, h4.w});
        }
        float h2last = tanh_fast(xv + ((aA.x + aA.y) + (aB.x + aB.y)));   // H2[512]

        float wfc[64];
        const int fr = lane & 31;
        const float4* fsrc = (const float4*)(Wfc1 + (size_t)fr * NH2);
#pragma unroll
        for (int i = 0; i < 16; ++i) {
            float4 v = fsrc[i];
            wfc[4*i+0] = v.x; wfc[4*i+1] = v.y;
            wfc[4*i+2] = v.z; wfc[4*i+3] = v.w;
        }
        float a = (lane < 32) ? bfc1[lane] : 0.0f;
#pragma unroll
        for (int k = 0; k < 64; ++k)
            a = fmaf(wfc[k], rlane(h2last, k), a);
        float v = (lane < 32) ? fmaxf(a, 0.0f) * Wfc2[lane] : 0.0f;
#pragma unroll
        for (int off = 16; off > 0; off >>= 1) v += __shfl_down(v, off);
        if (lane == 0) out[b] = v + bfc2[0];
    }
}

extern "C" void kernel_launch(void* const* d_in, const int* in_sizes, int n_in,
                              void* d_out, int out_size, void* d_ws, size_t ws_size,
                              hipStream_t stream) {
    const float* x     = (const float*)d_in[0];
    const float* Wih1  = (const float*)d_in[1];
    const float* Whh1  = (const float*)d_in[2];
    const float* bih1  = (const float*)d_in[3];
    const float* bhh1  = (const float*)d_in[4];
    const float* Wih2  = (const float*)d_in[5];
    const float* Whh2  = (const float*)d_in[6];
    const float* bih2  = (const float*)d_in[7];
    const float* bhh2  = (const float*)d_in[8];
    const float* Wfc1  = (const float*)d_in[9];
    const float* bfc1  = (const float*)d_in[10];
    const float* Wfc2  = (const float*)d_in[11];
    const float* bfc2  = (const float*)d_in[12];
    float* outp = (float*)d_out;

    float* xp1 = (float*)d_ws;   // 32768 x 128 fp32 = 16 MB

    xp1_gemm<<<dim3((NB * TT) / 128), dim3(256), 0, stream>>>(x, Wih1, bih1, bhh1, xp1);
    rnn_scan<<<dim3(NB), dim3(256), 0, stream>>>(xp1, Whh1, Wih2, Whh2, bih2, bhh2,
                                                 Wfc1, bfc1, Wfc2, bfc2, outp);
}

// Round 2
// 657.986 us; speedup vs baseline: 1.1147x; 1.0897x over previous
//
#include <hip/hip_runtime.h>

#define TT   512
#define DIN  2048
#define NH1  128
#define NH2  64
#define NB   64

typedef __attribute__((ext_vector_type(8))) __bf16 bf16x8;
typedef __attribute__((ext_vector_type(4))) float f32x4;
typedef __attribute__((ext_vector_type(2))) float f32x2;

__device__ __forceinline__ float tanh_fast(float x) {
    x = fminf(fmaxf(x, -15.0f), 15.0f);
    float e = __expf(2.0f * x);
    return (e - 1.0f) / (e + 1.0f);
}

__device__ __forceinline__ float rlane(float v, int l) {
    return __int_as_float(__builtin_amdgcn_readlane(__float_as_int(v), l));
}

// Packed fp32 FMA: 2 IEEE FMAs per VALU instruction (CDNA packed-f32 path).
__device__ __forceinline__ void pkfma(f32x2& acc, f32x2 w, f32x2 h) {
    asm("v_pk_fma_f32 %0, %1, %2, %0" : "+v"(acc) : "v"(w), "v"(h));
}

// Barrier WITHOUT vmcnt drain: LDS ordering only. Global loads stay in flight.
#define BAR() asm volatile("s_waitcnt lgkmcnt(0)\n\ts_barrier" ::: "memory")

// ---------------------------------------------------------------------------
// Kernel A: xp1 = x @ W_ih1^T + b  via 3-term bf16-split MFMA (~fp32 precision)
//   (unchanged — known-passing)
// ---------------------------------------------------------------------------
__global__ __launch_bounds__(256, 1) void xp1_gemm(const float* __restrict__ x,
                                                   const float* __restrict__ W,
                                                   const float* __restrict__ bih1,
                                                   const float* __restrict__ bhh1,
                                                   float* __restrict__ xp1) {
    __shared__ __align__(16) __bf16 wl[2][NH1][40];   // [plane][n][k pad 40]

    const int tid  = threadIdx.x;
    const int lane = tid & 63;
    const int wv   = tid >> 6;
    const int quad = lane >> 4;
    const int l16  = lane & 15;
    const int m0   = blockIdx.x * 128 + wv * 32;

    const int wr = tid >> 1;         // W stage: row
    const int wk = (tid & 1) * 16;   // W stage: k offset (16 fp32 per thread)

    float bias[8];
#pragma unroll
    for (int nt = 0; nt < 8; ++nt)
        bias[nt] = bih1[nt * 16 + l16] + bhh1[nt * 16 + l16];

    f32x4 acc[2][8];
#pragma unroll
    for (int ms = 0; ms < 2; ++ms)
#pragma unroll
        for (int nt = 0; nt < 8; ++nt)
            acc[ms][nt] = (f32x4){0.f, 0.f, 0.f, 0.f};

    const float* xr0 = x + (size_t)(m0 + l16) * DIN + quad * 8;
    const float* xr1 = x + (size_t)(m0 + 16 + l16) * DIN + quad * 8;
    const float* wp  = W + (size_t)wr * DIN + wk;

    // preload chunk 0
    float4 xa0 = *(const float4*)(xr0);
    float4 xb0 = *(const float4*)(xr0 + 4);
    float4 xa1 = *(const float4*)(xr1);
    float4 xb1 = *(const float4*)(xr1 + 4);
    float4 w0  = *(const float4*)(wp);
    float4 w1  = *(const float4*)(wp + 4);
    float4 w2  = *(const float4*)(wp + 8);
    float4 w3  = *(const float4*)(wp + 12);

    for (int kc = 0; kc < DIN; kc += 32) {
        // ---- convert & store W hi/lo planes (vmcnt wait auto-inserted)
        {
            float wf[16] = {w0.x, w0.y, w0.z, w0.w, w1.x, w1.y, w1.z, w1.w,
                            w2.x, w2.y, w2.z, w2.w, w3.x, w3.y, w3.z, w3.w};
            bf16x8 hv0, lv0, hv1, lv1;
#pragma unroll
            for (int j = 0; j < 8; ++j) {
                __bf16 h = (__bf16)wf[j];
                hv0[j] = h;
                lv0[j] = (__bf16)(wf[j] - (float)h);
            }
#pragma unroll
            for (int j = 0; j < 8; ++j) {
                __bf16 h = (__bf16)wf[8 + j];
                hv1[j] = h;
                lv1[j] = (__bf16)(wf[8 + j] - (float)h);
            }
            *(bf16x8*)&wl[0][wr][wk]     = hv0;
            *(bf16x8*)&wl[0][wr][wk + 8] = hv1;
            *(bf16x8*)&wl[1][wr][wk]     = lv0;
            *(bf16x8*)&wl[1][wr][wk + 8] = lv1;
        }
        BAR();

        // ---- convert current x to A-frags (before regs are overwritten)
        bf16x8 ah0, al0, ah1, al1;
        {
            float f0[8] = {xa0.x, xa0.y, xa0.z, xa0.w, xb0.x, xb0.y, xb0.z, xb0.w};
            float f1[8] = {xa1.x, xa1.y, xa1.z, xa1.w, xb1.x, xb1.y, xb1.z, xb1.w};
#pragma unroll
            for (int j = 0; j < 8; ++j) {
                __bf16 h0 = (__bf16)f0[j];
                ah0[j] = h0;
                al0[j] = (__bf16)(f0[j] - (float)h0);
                __bf16 h1 = (__bf16)f1[j];
                ah1[j] = h1;
                al1[j] = (__bf16)(f1[j] - (float)h1);
            }
        }

        // ---- prefetch next chunk (stays in flight through the MFMAs)
        if (kc + 32 < DIN) {
            xa0 = *(const float4*)(xr0 + kc + 32);
            xb0 = *(const float4*)(xr0 + kc + 36);
            xa1 = *(const float4*)(xr1 + kc + 32);
            xb1 = *(const float4*)(xr1 + kc + 36);
            w0  = *(const float4*)(wp + kc + 32);
            w1  = *(const float4*)(wp + kc + 36);
            w2  = *(const float4*)(wp + kc + 40);
            w3  = *(const float4*)(wp + kc + 44);
        }

        // ---- B-frags from LDS + 3-term MFMAs
#pragma unroll
        for (int nt = 0; nt < 8; ++nt) {
            bf16x8 bh = *(bf16x8*)&wl[0][nt * 16 + l16][quad * 8];
            bf16x8 bl = *(bf16x8*)&wl[1][nt * 16 + l16][quad * 8];
            acc[0][nt] = __builtin_amdgcn_mfma_f32_16x16x32_bf16(ah0, bh, acc[0][nt], 0, 0, 0);
            acc[0][nt] = __builtin_amdgcn_mfma_f32_16x16x32_bf16(al0, bh, acc[0][nt], 0, 0, 0);
            acc[0][nt] = __builtin_amdgcn_mfma_f32_16x16x32_bf16(ah0, bl, acc[0][nt], 0, 0, 0);
            acc[1][nt] = __builtin_amdgcn_mfma_f32_16x16x32_bf16(ah1, bh, acc[1][nt], 0, 0, 0);
            acc[1][nt] = __builtin_amdgcn_mfma_f32_16x16x32_bf16(al1, bh, acc[1][nt], 0, 0, 0);
            acc[1][nt] = __builtin_amdgcn_mfma_f32_16x16x32_bf16(ah1, bl, acc[1][nt], 0, 0, 0);
        }
        BAR();   // all reads done before next chunk's LDS overwrite
    }

    // ---- epilogue: C/D layout col=lane&15, row=quad*4+reg [m89-verified]
#pragma unroll
    for (int ms = 0; ms < 2; ++ms) {
        const int mb = m0 + ms * 16 + quad * 4;
#pragma unroll
        for (int nt = 0; nt < 8; ++nt) {
#pragma unroll
            for (int r = 0; r < 4; ++r)
                xp1[(size_t)(mb + r) * NH1 + nt * 16 + l16] = acc[ms][nt][r] + bias[nt];
        }
    }
}

// ---------------------------------------------------------------------------
// Kernel B: fused 2-layer scan + FC head. One block per batch elem, 4 waves.
// v3: LATENCY fix. v2 proved the scan is not VALU-bound (VALUBusy halved,
// time -5%): the ~1450 cyc/step came from shallow LDS pipelining — h was
// loaded one float4 at a time inside the FMA loop (VGPR=92 -> only ~8 loads
// in flight; ~6 serialized 120-cyc ds_read latency rounds per step).
// Fix: stage h into explicit register arrays (16 ds_read_b128 issued
// back-to-back per half), paying LDS latency ONCE per half. 1 wave/SIMD ->
// up to 512 VGPRs available, so the ~220-VGPR footprint is free.
// Accumulator partition and FMA order bit-identical to v2 (passing).
// ---------------------------------------------------------------------------
__global__ __launch_bounds__(256, 1) void rnn_scan(
        const float* __restrict__ xp1,  const float* __restrict__ Whh1,
        const float* __restrict__ Wih2, const float* __restrict__ Whh2,
        const float* __restrict__ bih2, const float* __restrict__ bhh2,
        const float* __restrict__ Wfc1, const float* __restrict__ bfc1,
        const float* __restrict__ Wfc2, const float* __restrict__ bfc2,
        float* __restrict__ out) {
    __shared__ __align__(16) float h1buf[2][NH1];
    __shared__ __align__(16) float xp2buf[2][NH2];
    __shared__ __align__(16) float h2buf[2][NH2];

    const int tid  = threadIdx.x;
    const int lane = tid & 63;
    const int wv   = tid >> 6;
    const int b    = blockIdx.x;

    // Per-lane weight row as aligned pairs (VGPR pairs for v_pk_fma_f32).
    f32x2 w2[64];
    float b2 = 0.0f;

    if (wv <= 1) {
        const int row = wv * 64 + lane;
        const float4* src = (const float4*)(Whh1 + (size_t)row * NH1);
#pragma unroll
        for (int i = 0; i < 32; ++i) {
            float4 v = src[i];
            w2[2 * i]     = (f32x2){v.x, v.y};
            w2[2 * i + 1] = (f32x2){v.z, v.w};
        }
    } else if (wv == 2) {
        const float4* src = (const float4*)(Wih2 + (size_t)lane * NH1);
#pragma unroll
        for (int i = 0; i < 32; ++i) {
            float4 v = src[i];
            w2[2 * i]     = (f32x2){v.x, v.y};
            w2[2 * i + 1] = (f32x2){v.z, v.w};
        }
        b2 = bih2[lane] + bhh2[lane];
    } else {
        const float4* src = (const float4*)(Whh2 + (size_t)lane * NH2);
#pragma unroll
        for (int i = 0; i < 16; ++i) {
            float4 v = src[i];
            w2[2 * i]     = (f32x2){v.x, v.y};
            w2[2 * i + 1] = (f32x2){v.z, v.w};
        }
    }

    if (tid < 128) h1buf[0][tid] = 0.0f;
    if (tid < 64)  { h2buf[0][tid] = 0.0f; h2buf[1][tid] = 0.0f; }

    const int row = wv * 64 + lane;
    const float* xprow = xp1 + ((size_t)b * TT) * NH1 + row;

    float xr[8], xrn[8];
    if (wv <= 1) {
#pragma unroll
        for (int j = 0; j < 8; ++j) xr[j] = xprow[(size_t)j * NH1];
    }

    __syncthreads();   // one-time init barrier

    for (int g = 0; g < 64; ++g) {
        if (wv <= 1 && g < 63) {
            const size_t t0 = (size_t)(g + 1) * 8;
#pragma unroll
            for (int j = 0; j < 8; ++j) xrn[j] = xprow[(t0 + j) * NH1];
        }
#pragma unroll
        for (int j = 0; j < 8; ++j) {           // step s = 8g + j + 1
            const int s   = 8 * g + j + 1;
            const int cur = j & 1;
            const int nxt = cur ^ 1;
            if (wv <= 1) {
                // h1[s] = tanh(xp1[s] + Whh1 . h1[s-1]); h1[s-1] in h1buf[cur]
                const f32x4* hb4 = (const f32x4*)&h1buf[cur][0];
                f32x4 ha[16];                        // h[0..63] staged: 16
#pragma unroll                                       // ds_read_b128 back-to-back
                for (int i = 0; i < 16; ++i) ha[i] = hb4[i];
                f32x2 aA = (f32x2){xr[j], 0.0f};
                f32x2 aB = (f32x2){0.0f, 0.0f};
#pragma unroll
                for (int i = 0; i < 16; ++i) {
                    pkfma(aA, w2[2 * i],     (f32x2){ha[i].x, ha[i].y});
                    pkfma(aB, w2[2 * i + 1], (f32x2){ha[i].z, ha[i].w});
                }
                f32x4 hc[16];                        // h[64..127] (loads float
#pragma unroll                                       // up into the FMA block)
                for (int i = 0; i < 16; ++i) hc[i] = hb4[16 + i];
#pragma unroll
                for (int i = 0; i < 16; ++i) {
                    pkfma(aA, w2[32 + 2 * i],     (f32x2){hc[i].x, hc[i].y});
                    pkfma(aB, w2[32 + 2 * i + 1], (f32x2){hc[i].z, hc[i].w});
                }
                float hv = tanh_fast((aA.x + aA.y) + (aB.x + aB.y));
                h1buf[nxt][row] = hv;
            } else if (wv == 2) {
                if (s >= 2) {
                    // xp2[s-1] = b2 + Wih2 . h1[s-1]
                    const f32x4* hb4 = (const f32x4*)&h1buf[cur][0];
                    f32x4 ha[16];
#pragma unroll
                    for (int i = 0; i < 16; ++i) ha[i] = hb4[i];
                    f32x2 aA = (f32x2){b2, 0.0f};
                    f32x2 aB = (f32x2){0.0f, 0.0f};
#pragma unroll
                    for (int i = 0; i < 16; ++i) {
                        pkfma(aA, w2[2 * i],     (f32x2){ha[i].x, ha[i].y});
                        pkfma(aB, w2[2 * i + 1], (f32x2){ha[i].z, ha[i].w});
                    }
                    f32x4 hc[16];
#pragma unroll
                    for (int i = 0; i < 16; ++i) hc[i] = hb4[16 + i];
#pragma unroll
                    for (int i = 0; i < 16; ++i) {
                        pkfma(aA, w2[32 + 2 * i],     (f32x2){hc[i].x, hc[i].y});
                        pkfma(aB, w2[32 + 2 * i + 1], (f32x2){hc[i].z, hc[i].w});
                    }
                    xp2buf[j & 1][lane] = (aA.x + aA.y) + (aB.x + aB.y);
                }
            } else {
                if (s >= 3) {
                    // h2[s-2] = tanh(xp2[s-2] + Whh2 . h2[s-3]); state in h2buf[cur]
                    float xv = xp2buf[(j + 1) & 1][lane];
                    const f32x4* hb4 = (const f32x4*)&h2buf[cur][0];
                    f32x4 ha[16];                    // all 64 h2 values staged
#pragma unroll
                    for (int i = 0; i < 16; ++i) ha[i] = hb4[i];
                    f32x2 aA = (f32x2){0.0f, 0.0f};
                    f32x2 aB = (f32x2){0.0f, 0.0f};
#pragma unroll
                    for (int i = 0; i < 16; ++i) {
                        pkfma(aA, w2[2 * i],     (f32x2){ha[i].x, ha[i].y});
                        pkfma(aB, w2[2 * i + 1], (f32x2){ha[i].z, ha[i].w});
                    }
                    float h2v = tanh_fast(xv + ((aA.x + aA.y) + (aB.x + aB.y)));
                    h2buf[nxt][lane] = h2v;
                }
            }
            BAR();
        }
        if (wv <= 1 && g < 63) {
#pragma unroll
            for (int j = 0; j < 8; ++j) xr[j] = xrn[j];
        }
    }

    // tail s = 513: wave2 makes xp2[512]; wave3 makes h2[511]
    {
        if (wv == 2) {
            f32x2 aA = (f32x2){b2, 0.0f};
            f32x2 aB = (f32x2){0.0f, 0.0f};
#pragma unroll
            for (int i = 0; i < 32; ++i) {
                float4 h4 = *(const float4*)&h1buf[0][4 * i];   // H1[512]
                pkfma(aA, w2[2 * i],     (f32x2){h4.x, h4.y});
                pkfma(aB, w2[2 * i + 1], (f32x2){h4.z, h4.w});
            }
            xp2buf[0][lane] = (aA.x + aA.y) + (aB.x + aB.y);    // xp2[512]+bias
        } else if (wv == 3) {
            float xv = xp2buf[1][lane];                         // xp2[511]+bias
            f32x2 aA = (f32x2){0.0f, 0.0f};
            f32x2 aB = (f32x2){0.0f, 0.0f};
#pragma unroll
            for (int i = 0; i < 16; ++i) {
                float4 h4 = *(const float4*)&h2buf[0][4 * i];   // h2[510]
                pkfma(aA, w2[2 * i],     (f32x2){h4.x, h4.y});
                pkfma(aB, w2[2 * i + 1], (f32x2){h4.z, h4.w});
            }
            float h2v = tanh_fast(xv + ((aA.x + aA.y) + (aB.x + aB.y)));  // h2[511]
            h2buf[1][lane] = h2v;
        }
        BAR();
    }
    // tail s = 514: wave3 makes H2[512]; then FC head
    if (wv == 3) {
        float xv = xp2buf[0][lane];                             // xp2[512]+bias
        f32x2 aA = (f32x2){0.0f, 0.0f};
        f32x2 aB = (f32x2){0.0f, 0.0f};
#pragma unroll
        for (int i = 0; i < 16; ++i) {
            float4 h4 = *(const float4*)&h2buf[1][4 * i];       // h2[511]
            pkfma(aA, w2[2 * i],     (f32x2){h4.x, h4.y});
            pkfma(aB, w2[2 * i + 1], (f32x2){h4.z, h4.w});
        }
        float h2last = tanh_fast(xv + ((aA.x + aA.y) + (aB.x + aB.y)));   // H2[512]

        float wfc[64];
        const int fr = lane & 31;
        const float4* fsrc = (const float4*)(Wfc1 + (size_t)fr * NH2);
#pragma unroll
        for (int i = 0; i < 16; ++i) {
            float4 v = fsrc[i];
            wfc[4*i+0] = v.x; wfc[4*i+1] = v.y;
            wfc[4*i+2] = v.z; wfc[4*i+3] = v.w;
        }
        float a = (lane < 32) ? bfc1[lane] : 0.0f;
#pragma unroll
        for (int k = 0; k < 64; ++k)
            a = fmaf(wfc[k], rlane(h2last, k), a);
        float v = (lane < 32) ? fmaxf(a, 0.0f) * Wfc2[lane] : 0.0f;
#pragma unroll
        for (int off = 16; off > 0; off >>= 1) v += __shfl_down(v, off);
        if (lane == 0) out[b] = v + bfc2[0];
    }
}

extern "C" void kernel_launch(void* const* d_in, const int* in_sizes, int n_in,
                              void* d_out, int out_size, void* d_ws, size_t ws_size,
                              hipStream_t stream) {
    const float* x     = (const float*)d_in[0];
    const float* Wih1  = (const float*)d_in[1];
    const float* Whh1  = (const float*)d_in[2];
    const float* bih1  = (const float*)d_in[3];
    const float* bhh1  = (const float*)d_in[4];
    const float* Wih2  = (const float*)d_in[5];
    const float* Whh2  = (const float*)d_in[6];
    const float* bih2  = (const float*)d_in[7];
    const float* bhh2  = (const float*)d_in[8];
    const float* Wfc1  = (const float*)d_in[9];
    const float* bfc1  = (const float*)d_in[10];
    const float* Wfc2  = (const float*)d_in[11];
    const float* bfc2  = (const float*)d_in[12];
    float* outp = (float*)d_out;

    float* xp1 = (float*)d_ws;   // 32768 x 128 fp32 = 16 MB

    xp1_gemm<<<dim3((NB * TT) / 128), dim3(256), 0, stream>>>(x, Wih1, bih1, bhh1, xp1);
    rnn_scan<<<dim3(NB), dim3(256), 0, stream>>>(xp1, Whh1, Wih2, Whh2, bih2, bhh2,
                                                 Wfc1, bfc1, Wfc2, bfc2, outp);
}